// Round 12
// baseline (3558.906 us; speedup 1.0000x reference)
//
#include <hip/hip_runtime.h>
#include <hip/hip_bf16.h>
#include <math.h>

// Problem constants
// B=32, T=12, N=2048, C=1, D=10, K=2, H=32
#define NNODE 2048
#define NB 32
#define NT 12
#define NH 32
#define ND 10
#define NCOL 1024          // h columns
#define NCX 384            // (t,b) x columns
#define KPAD 96            // gconv K = 66, zero-padded to 3 MFMA k-tiles
#define GPAD 104           // LDS row stride (halfs) for cat tiles
#define WPAD 98            // LDS row stride for wg/wu transpose

#define ASCALE 256.0f
#define AINV 0.00390625f

#define KCHUNK 512
#define Y1S ((size_t)NNODE * NCOL)
#define AXPS ((size_t)NNODE * NCX)

typedef _Float16 half8 __attribute__((ext_vector_type(8)));
typedef float floatx4 __attribute__((ext_vector_type(4)));

#define AS1 __attribute__((address_space(1)))
#define AS3 __attribute__((address_space(3)))
__device__ __forceinline__ void gload16(const _Float16* g, _Float16* l) {
    __builtin_amdgcn_global_load_lds((const AS1 unsigned int*)(g),
                                     (AS3 unsigned int*)(l), 16, 0, 0);
}

// ---------------- workspace layout (float slots) ----------------
constexpr size_t OFF_AH  = 0;
constexpr size_t OFF_WGT = OFF_AH + 2097152u;
constexpr size_t OFF_WUT = OFF_WGT + 6291456u;
constexpr size_t OFF_BG  = OFF_WUT + 3145728u;
constexpr size_t OFF_BU  = OFF_BG + 131072u;
constexpr size_t OFF_XT  = OFF_BU + 65536u;
constexpr size_t OFF_X2T = OFF_XT + 1048576u;
constexpr size_t OFF_SXT = OFF_X2T + 1048576u;
constexpr size_t OFF_HS  = OFF_SXT + 393216u;
constexpr size_t OFF_Y   = OFF_HS + 2097152u;
constexpr size_t OFF_AXP = OFF_Y + 4194304u;
constexpr size_t OFF_R   = OFF_AXP + 1572864u;
constexpr size_t OFF_ZH  = OFF_R + 1048576u;
constexpr size_t OFF_CNT = OFF_ZH + 1048576u;   // 24 slabs x 16 unsigned = 384
// end = 24,183,168 floats = ~96.7 MB

// ---------------- A = softmax(relu(E E^T), axis=1) * ASCALE, fp16 ----------------
__global__ __launch_bounds__(256) void adj_kernel(const float* __restrict__ E,
                                                  _Float16* __restrict__ Ah) {
    __shared__ float En[ND];
    __shared__ float red[256];
    const int n = blockIdx.x;
    const int t = threadIdx.x;
    if (t < ND) En[t] = E[n * ND + t];
    __syncthreads();
    float v[8];
    float mx = 0.f;
#pragma unroll
    for (int i = 0; i < 8; ++i) {
        const int m = t + i * 256;
        float acc = 0.f;
#pragma unroll
        for (int d = 0; d < ND; ++d) acc += En[d] * E[m * ND + d];
        acc = fmaxf(acc, 0.f);
        v[i] = acc;
        mx = fmaxf(mx, acc);
    }
    red[t] = mx;
    __syncthreads();
    for (int s = 128; s > 0; s >>= 1) {
        if (t < s) red[t] = fmaxf(red[t], red[t + s]);
        __syncthreads();
    }
    mx = red[0];
    __syncthreads();
    float sum = 0.f;
#pragma unroll
    for (int i = 0; i < 8; ++i) {
        v[i] = expf(v[i] - mx);
        sum += v[i];
    }
    red[t] = sum;
    __syncthreads();
    for (int s = 128; s > 0; s >>= 1) {
        if (t < s) red[t] += red[t + s];
        __syncthreads();
    }
    const float inv = ASCALE / red[0];
#pragma unroll
    for (int i = 0; i < 8; ++i)
        Ah[(size_t)n * NNODE + t + i * 256] = (_Float16)(v[i] * inv);
}

// ---------------- per-node weights -> [n][o][k] via LDS transpose ----------------
__global__ __launch_bounds__(256) void wg_kernel(const float* __restrict__ E,
                                                 const float* __restrict__ gW,
                                                 _Float16* __restrict__ Wgt) {
    __shared__ float Es[ND];
    __shared__ _Float16 Wl[64 * WPAD];
    const int n = blockIdx.x, t = threadIdx.x;
    if (t < ND) Es[t] = E[n * ND + t];
    for (int i = t; i < 64 * WPAD / 2; i += 256) ((unsigned*)Wl)[i] = 0u;
    __syncthreads();
    for (int rem = t; rem < 4224; rem += 256) {
        float acc = 0.f;
#pragma unroll
        for (int d = 0; d < ND; ++d) acc += Es[d] * gW[d * 4224 + rem];
        const int kk = rem / 2112, r2 = rem % 2112;
        const int i = r2 >> 6, o = r2 & 63;
        Wl[o * WPAD + kk * 33 + i] = (_Float16)acc;
    }
    __syncthreads();
    const unsigned* wl = (const unsigned*)Wl;
    unsigned* dst = (unsigned*)(Wgt + (size_t)n * 6144);
    for (int idx = t; idx < 64 * 48; idx += 256) {
        const int o = idx / 48, j = idx % 48;
        dst[idx] = wl[o * (WPAD / 2) + j];
    }
}

__global__ __launch_bounds__(256) void wu_kernel(const float* __restrict__ E,
                                                 const float* __restrict__ uW,
                                                 _Float16* __restrict__ Wut) {
    __shared__ float Es[ND];
    __shared__ _Float16 Wl[32 * WPAD];
    const int n = blockIdx.x, t = threadIdx.x;
    if (t < ND) Es[t] = E[n * ND + t];
    for (int i = t; i < 32 * WPAD / 2; i += 256) ((unsigned*)Wl)[i] = 0u;
    __syncthreads();
    for (int rem = t; rem < 2112; rem += 256) {
        float acc = 0.f;
#pragma unroll
        for (int d = 0; d < ND; ++d) acc += Es[d] * uW[d * 2112 + rem];
        const int kk = rem / 1056, r2 = rem % 1056;
        const int i = r2 >> 5, o = r2 & 31;
        Wl[o * WPAD + kk * 33 + i] = (_Float16)acc;
    }
    __syncthreads();
    const unsigned* wl = (const unsigned*)Wl;
    unsigned* dst = (unsigned*)(Wut + (size_t)n * 3072);
    for (int idx = t; idx < 32 * 48; idx += 256) {
        const int o = idx / 48, j = idx % 48;
        dst[idx] = wl[o * (WPAD / 2) + j];
    }
}

__global__ __launch_bounds__(256) void bias_kernel(const float* __restrict__ E,
                                                   const float* __restrict__ gb,
                                                   const float* __restrict__ ub,
                                                   float* __restrict__ bg,
                                                   float* __restrict__ bu) {
    const int idx = blockIdx.x * 256 + threadIdx.x;
    if (idx < NNODE * 64) {
        const int n = idx >> 6, o = idx & 63;
        float acc = 0.f;
#pragma unroll
        for (int d = 0; d < ND; ++d) acc += E[n * ND + d] * gb[d * 64 + o];
        bg[idx] = acc;
    } else if (idx < NNODE * 64 + NNODE * 32) {
        const int j = idx - NNODE * 64;
        const int n = j >> 5, o = j & 31;
        float acc = 0.f;
#pragma unroll
        for (int d = 0; d < ND; ++d) acc += E[n * ND + d] * ub[d * 32 + o];
        bu[j] = acc;
    }
}

// ---------------- init: XT=0, X2T=0, Hs=0, SXT from src, cnt slabs = 0 ----------------
__global__ __launch_bounds__(256) void setup_kernel(const float* __restrict__ src,
                                                    _Float16* __restrict__ XT,
                                                    _Float16* __restrict__ X2T,
                                                    _Float16* __restrict__ SXT,
                                                    float* __restrict__ Hs,
                                                    unsigned* __restrict__ cnt) {
    const int idx = blockIdx.x * 256 + threadIdx.x;  // over 2048*1024
    XT[idx] = (_Float16)0.f;
    X2T[idx] = (_Float16)0.f;
    Hs[idx] = 0.f;
    if (idx < NCX * NNODE) {
        const int col = idx >> 11, n = idx & 2047;
        const int tt = col >> 5, b = col & 31;
        SXT[idx] = (_Float16)src[((size_t)b * NT + tt) * NNODE + n];
    }
    if (idx < 384) cnt[idx] = 0u;
}

// ---------------- mm tile task (device body; R9 decode) ----------------
__device__ __forceinline__ void mm_tile(const _Float16* __restrict__ Ah,
                                        const _Float16* __restrict__ XT,
                                        _Float16* __restrict__ Y, int nct,
                                        int task, int t, _Float16* As, _Float16* Bs) {
    const int xcd = task & 7;
    const int kz = xcd >> 1;
    const int s = (task >> 3) * 2 + (xcd & 1);
    const int m0 = (s & 15) * 128;
    const int c0 = (s >> 4) * 128;
    const int ncols = nct << 7;
    _Float16* __restrict__ Yp = Y + (size_t)kz * NNODE * ncols;
    const int lane = t & 63;
    const int w = t >> 6;
    const int wm = (w & 1) * 64;
    const int wn = (w >> 1) * 64;
    const int lm = lane & 15;
    const int q = lane >> 4;

    const int srow = w * 32 + (lane >> 2);
    const int sq = (lane & 3) ^ ((lane >> 3) & 3);
    const _Float16* gA = Ah + (size_t)(m0 + srow) * NNODE + kz * KCHUNK + sq * 8;
    const _Float16* gB = XT + (size_t)(c0 + srow) * NNODE + kz * KCHUNK + sq * 8;
    _Float16* lA = As + w * 1024;
    _Float16* lB = Bs + w * 1024;
    const int fp = (q ^ ((lm >> 1) & 3)) * 8;

    floatx4 acc[4][4] = {};

    for (int kt = 0; kt < KCHUNK; kt += 32) {
        gload16(gA, lA);
        gload16(gA + 16 * NNODE, lA + 512);
        gload16(gB, lB);
        gload16(gB + 16 * NNODE, lB + 512);
        gA += 32;
        gB += 32;
        __syncthreads();
        half8 af[4], bf[4];
#pragma unroll
        for (int mt = 0; mt < 4; ++mt)
            af[mt] = *(const half8*)&As[(wm + mt * 16 + lm) * 32 + fp];
#pragma unroll
        for (int nt = 0; nt < 4; ++nt)
            bf[nt] = *(const half8*)&Bs[(wn + nt * 16 + lm) * 32 + fp];
#pragma unroll
        for (int mt = 0; mt < 4; ++mt)
#pragma unroll
            for (int nt = 0; nt < 4; ++nt)
                acc[mt][nt] = __builtin_amdgcn_mfma_f32_16x16x32_f16(
                    af[mt], bf[nt], acc[mt][nt], 0, 0, 0);
        __syncthreads();
    }
#pragma unroll
    for (int mt = 0; mt < 4; ++mt) {
#pragma unroll
        for (int nt = 0; nt < 4; ++nt) {
            const int row = m0 + wm + mt * 16 + q * 4;
            const int col = c0 + wn + nt * 16 + lm;
#pragma unroll
            for (int r = 0; r < 4; ++r)
                Yp[(size_t)(row + r) * ncols + col] = (_Float16)(acc[mt][nt][r] * AINV);
        }
    }
}

// signal my row-block done; wait (RELAXED spin, single acquire) for consumer row-block
__device__ __forceinline__ void signal_wait(unsigned* cnt, int bid, int t) {
    __threadfence();   // make this block's Y stores device-visible
    __syncthreads();
    if (t == 0) {
        const int sp = (bid >> 3) * 2 + (bid & 1);     // produced row-block = sp & 15
        __hip_atomic_fetch_add(&cnt[sp & 15], 1u, __ATOMIC_RELEASE,
                               __HIP_MEMORY_SCOPE_AGENT);
        const int rc = bid >> 5;                        // consumed row-block
        unsigned v;
        do {
            v = __hip_atomic_load(&cnt[rc], __ATOMIC_RELAXED, __HIP_MEMORY_SCOPE_AGENT);
            if (v < 32u) __builtin_amdgcn_s_sleep(1);
        } while (v < 32u);
        (void)__hip_atomic_load(&cnt[rc], __ATOMIC_ACQUIRE, __HIP_MEMORY_SCOPE_AGENT);
    }
    __syncthreads();
}

#define CAT(nd, b, i) cat[((nd) * 32 + (b)) * GPAD + (i)]

// ---------------- K1: mm1 (Y = A @ XT) fused with gate ----------------
__global__ __launch_bounds__(256, 2) void mmgate_kernel(
    const float* __restrict__ src, int tcur, const _Float16* __restrict__ Ah,
    const _Float16* __restrict__ XT, _Float16* __restrict__ Y,
    const _Float16* __restrict__ AXP, const _Float16* __restrict__ Wgt,
    const float* __restrict__ bg, const float* __restrict__ Hs,
    _Float16* __restrict__ X2T, _Float16* __restrict__ zh,
    _Float16* __restrict__ rbuf, unsigned* __restrict__ cnt) {
    __shared__ __align__(16) _Float16 smem[4 * 32 * GPAD];
    _Float16* As = smem;
    _Float16* Bs = smem + 4096;
    _Float16* cat = smem;
    const int t = threadIdx.x, bid = blockIdx.x;
    const int w = t >> 6, lane = t & 63, lm = lane & 15, q = lane >> 4;

    mm_tile(Ah, XT, Y, 8, bid, t, As, Bs);
    signal_wait(cnt, bid, t);

    // gate for node group bid (nodes 4*bid .. 4*bid+3)
    const int n0 = bid * 4;
    {
        const int pair = t >> 1, which = t & 1;
        const int nd = pair >> 5, b = pair & 31;
        const int n1 = n0 + nd;
        if (which == 0) {
            CAT(nd, b, 0) = (_Float16)src[((size_t)b * NT + tcur) * NNODE + n1];
            const float* hp = Hs + (size_t)n1 * 1024 + b * 32;
#pragma unroll
            for (int i = 0; i < 32; ++i) CAT(nd, b, 1 + i) = (_Float16)hp[i];
#pragma unroll
            for (int i = 66; i < KPAD; i += 2) *(unsigned*)&CAT(nd, b, i) = 0u;
        } else {
            const _Float16* ax = AXP + (size_t)n1 * NCX + tcur * 32 + b;
            CAT(nd, b, 33) = (_Float16)((float)ax[0] + (float)ax[AXPS] +
                                        (float)ax[2 * AXPS] + (float)ax[3 * AXPS]);
            const _Float16* yp = Y + (size_t)n1 * NCOL + b * 32;
#pragma unroll
            for (int i = 0; i < 32; ++i) {
                const float sv = (float)yp[i] + (float)yp[Y1S + i] +
                                 (float)yp[2 * Y1S + i] + (float)yp[3 * Y1S + i];
                CAT(nd, b, 34 + i) = (_Float16)sv;
            }
        }
    }
    __syncthreads();
    const int n = n0 + w;
    const _Float16* Wn = Wgt + (size_t)n * 6144;
    floatx4 acc[2][4] = {};
#pragma unroll
    for (int kt = 0; kt < 3; ++kt) {
        half8 af[2], bf[4];
#pragma unroll
        for (int mt = 0; mt < 2; ++mt)
            af[mt] = *(const half8*)&CAT(w, mt * 16 + lm, kt * 32 + q * 8);
#pragma unroll
        for (int nt = 0; nt < 4; ++nt)
            bf[nt] = *(const half8*)(Wn + (nt * 16 + lm) * KPAD + kt * 32 + q * 8);
#pragma unroll
        for (int mt = 0; mt < 2; ++mt)
#pragma unroll
            for (int nt = 0; nt < 4; ++nt)
                acc[mt][nt] = __builtin_amdgcn_mfma_f32_16x16x32_f16(
                    af[mt], bf[nt], acc[mt][nt], 0, 0, 0);
    }
#pragma unroll
    for (int nt = 0; nt < 4; ++nt) {
        const int o = nt * 16 + lm;
        const float bias = bg[n * 64 + o];
#pragma unroll
        for (int mt = 0; mt < 2; ++mt) {
#pragma unroll
            for (int r = 0; r < 4; ++r) {
                const int b = mt * 16 + q * 4 + r;
                const float s = 1.f / (1.f + expf(-(acc[mt][nt][r] + bias)));
                if (o < 32) {
                    const float hold = Hs[(size_t)n * 1024 + b * 32 + o];
                    const _Float16 zv = (_Float16)(s * hold);
                    zh[(size_t)n * 1024 + b * 32 + o] = zv;
                    X2T[(size_t)(b * 32 + o) * NNODE + n] = zv;
                } else {
                    rbuf[(size_t)n * 1024 + b * 32 + (o - 32)] = (_Float16)s;
                }
            }
        }
    }
}

// ---------------- K2: mm2 (Y = A @ X2T) fused with update ----------------
__global__ __launch_bounds__(256, 2) void mmupd_kernel(
    const float* __restrict__ src, int tcur, const _Float16* __restrict__ Ah,
    const _Float16* __restrict__ X2T, _Float16* __restrict__ Y,
    const _Float16* __restrict__ AXP, const _Float16* __restrict__ Wut,
    const float* __restrict__ bu, const _Float16* __restrict__ zh,
    const _Float16* __restrict__ rbuf, float* __restrict__ Hs,
    _Float16* __restrict__ XT, unsigned* __restrict__ cnt) {
    __shared__ __align__(16) _Float16 smem[4 * 32 * GPAD];
    _Float16* As = smem;
    _Float16* Bs = smem + 4096;
    _Float16* cat = smem;
    const int t = threadIdx.x, bid = blockIdx.x;
    const int w = t >> 6, lane = t & 63, lm = lane & 15, q = lane >> 4;

    mm_tile(Ah, X2T, Y, 8, bid, t, As, Bs);
    signal_wait(cnt, bid, t);

    const int n0 = bid * 4;
    {
        const int pair = t >> 1, which = t & 1;
        const int nd = pair >> 5, b = pair & 31;
        const int n1 = n0 + nd;
        if (which == 0) {
            CAT(nd, b, 0) = (_Float16)src[((size_t)b * NT + tcur) * NNODE + n1];
            const _Float16* zp = zh + (size_t)n1 * 1024 + b * 32;
#pragma unroll
            for (int i = 0; i < 32; ++i) CAT(nd, b, 1 + i) = zp[i];
#pragma unroll
            for (int i = 66; i < KPAD; i += 2) *(unsigned*)&CAT(nd, b, i) = 0u;
        } else {
            const _Float16* ax = AXP + (size_t)n1 * NCX + tcur * 32 + b;
            CAT(nd, b, 33) = (_Float16)((float)ax[0] + (float)ax[AXPS] +
                                        (float)ax[2 * AXPS] + (float)ax[3 * AXPS]);
            const _Float16* yp = Y + (size_t)n1 * NCOL + b * 32;
#pragma unroll
            for (int i = 0; i < 32; ++i) {
                const float sv = (float)yp[i] + (float)yp[Y1S + i] +
                                 (float)yp[2 * Y1S + i] + (float)yp[3 * Y1S + i];
                CAT(nd, b, 34 + i) = (_Float16)sv;
            }
        }
    }
    __syncthreads();
    const int n = n0 + w;
    const _Float16* Wn = Wut + (size_t)n * 3072;
    floatx4 acc[2][2] = {};
#pragma unroll
    for (int kt = 0; kt < 3; ++kt) {
        half8 af[2], bf[2];
#pragma unroll
        for (int mt = 0; mt < 2; ++mt)
            af[mt] = *(const half8*)&CAT(w, mt * 16 + lm, kt * 32 + q * 8);
#pragma unroll
        for (int nt = 0; nt < 2; ++nt)
            bf[nt] = *(const half8*)(Wn + (nt * 16 + lm) * KPAD + kt * 32 + q * 8);
#pragma unroll
        for (int mt = 0; mt < 2; ++mt)
#pragma unroll
            for (int nt = 0; nt < 2; ++nt)
                acc[mt][nt] = __builtin_amdgcn_mfma_f32_16x16x32_f16(
                    af[mt], bf[nt], acc[mt][nt], 0, 0, 0);
    }
#pragma unroll
    for (int nt = 0; nt < 2; ++nt) {
        const int o = nt * 16 + lm;
        const float bias = bu[n * 32 + o];
#pragma unroll
        for (int mt = 0; mt < 2; ++mt) {
#pragma unroll
            for (int r = 0; r < 4; ++r) {
                const int b = mt * 16 + q * 4 + r;
                const float hc = tanhf(acc[mt][nt][r] + bias);
                const float rr = (float)rbuf[(size_t)n * 1024 + b * 32 + o];
                const size_t hidx = (size_t)n * 1024 + b * 32 + o;
                const float hnew = rr * Hs[hidx] + (1.f - rr) * hc;
                Hs[hidx] = hnew;
                XT[(size_t)(b * 32 + o) * NNODE + n] = (_Float16)hnew;
            }
        }
    }
}

// ---------------- standalone mm (AXP precompute) ----------------
__global__ __launch_bounds__(256) void mm_kernel(const _Float16* __restrict__ Ah,
                                                 const _Float16* __restrict__ XT,
                                                 _Float16* __restrict__ Y, int nct) {
    __shared__ __align__(16) _Float16 smem[8192];
    mm_tile(Ah, XT, Y, nct, blockIdx.x, threadIdx.x, smem, smem + 4096);
}

// ---------------- out[b,0,n,t] ----------------
__global__ __launch_bounds__(256) void out_kernel(const float* __restrict__ Hs,
                                                  const float* __restrict__ cw,
                                                  const float* __restrict__ cb,
                                                  float* __restrict__ out) {
    __shared__ float h[NB * NH];
    __shared__ float cws[NT * NH];
    __shared__ float cbs[NT];
    const int n = blockIdx.x;
    const int t = threadIdx.x;
    for (int i = t; i < NT * NH; i += 256) cws[i] = cw[i];
    if (t < NT) cbs[t] = cb[t];
    for (int i = t; i < NB * NH; i += 256) h[i] = Hs[(size_t)n * 1024 + i];
    __syncthreads();
    for (int p = t; p < NB * NT; p += 256) {
        const int b = p / NT, tt = p % NT;
        float acc = cbs[tt];
#pragma unroll
        for (int j = 0; j < NH; ++j) acc += h[b * NH + j] * cws[tt * NH + j];
        out[(size_t)b * NNODE * NT + (size_t)n * NT + tt] = acc;
    }
}

extern "C" void kernel_launch(void* const* d_in, const int* in_sizes, int n_in,
                              void* d_out, int out_size, void* d_ws, size_t ws_size,
                              hipStream_t stream) {
    const float* src  = (const float*)d_in[0];
    const float* E    = (const float*)d_in[1];
    const float* gW   = (const float*)d_in[2];
    const float* gb   = (const float*)d_in[3];
    const float* uW   = (const float*)d_in[4];
    const float* ub   = (const float*)d_in[5];
    const float* cw   = (const float*)d_in[6];
    const float* cb   = (const float*)d_in[7];
    float* out = (float*)d_out;

    float* ws = (float*)d_ws;
    _Float16* Ah  = (_Float16*)(ws + OFF_AH);
    _Float16* Wgt = (_Float16*)(ws + OFF_WGT);
    _Float16* Wut = (_Float16*)(ws + OFF_WUT);
    float* bg  = ws + OFF_BG;
    float* bu  = ws + OFF_BU;
    _Float16* XT  = (_Float16*)(ws + OFF_XT);
    _Float16* X2T = (_Float16*)(ws + OFF_X2T);
    _Float16* SXT = (_Float16*)(ws + OFF_SXT);
    float* Hs  = ws + OFF_HS;
    _Float16* Y   = (_Float16*)(ws + OFF_Y);
    _Float16* AXP = (_Float16*)(ws + OFF_AXP);
    _Float16* rb  = (_Float16*)(ws + OFF_R);
    _Float16* zh  = (_Float16*)(ws + OFF_ZH);
    unsigned* cnt = (unsigned*)(ws + OFF_CNT);

    adj_kernel<<<NNODE, 256, 0, stream>>>(E, Ah);
    wg_kernel<<<NNODE, 256, 0, stream>>>(E, gW, Wgt);
    wu_kernel<<<NNODE, 256, 0, stream>>>(E, uW, Wut);
    bias_kernel<<<(NNODE * 96 + 255) / 256, 256, 0, stream>>>(E, gb, ub, bg, bu);
    setup_kernel<<<NNODE * NCOL / 256, 256, 0, stream>>>(src, XT, X2T, SXT, Hs, cnt);

    // A @ x_t for all 12 steps at once (384 cols, 3 col-tiles)
    mm_kernel<<<64 * 3, 256, 0, stream>>>(Ah, SXT, AXP, 3);

    for (int t = 0; t < NT; ++t) {
        mmgate_kernel<<<512, 256, 0, stream>>>(src, t, Ah, XT, Y, AXP, Wgt, bg,
                                               Hs, X2T, zh, rb, cnt + 32 * t);
        mmupd_kernel<<<512, 256, 0, stream>>>(src, t, Ah, X2T, Y, AXP, Wut, bu,
                                              zh, rb, Hs, XT, cnt + 32 * t + 16);
    }
    out_kernel<<<NNODE, 256, 0, stream>>>(Hs, cw, cb, out);
}

// Round 13
// 1109.015 us; speedup vs baseline: 3.2091x; 3.2091x over previous
//
#include <hip/hip_runtime.h>
#include <hip/hip_bf16.h>
#include <math.h>

// Problem constants
// B=32, T=12, N=2048, C=1, D=10, K=2, H=32
#define NNODE 2048
#define NB 32
#define NT 12
#define NH 32
#define ND 10
#define NCOL 1024          // h columns
#define NCX 384            // (t,b) x columns
#define KPAD 96            // gconv K = 66, zero-padded to 3 MFMA k-tiles
#define GPAD 104           // LDS row stride (halfs) for cat tiles
#define WPAD 98            // LDS row stride for wg/wu transpose

#define ASCALE 256.0f
#define AINV 0.00390625f

#define KCHUNK 512
#define Y1S ((size_t)NNODE * NCOL)
#define AXPS ((size_t)NNODE * NCX)

typedef _Float16 half8 __attribute__((ext_vector_type(8)));
typedef float floatx4 __attribute__((ext_vector_type(4)));

#define AS1 __attribute__((address_space(1)))
#define AS3 __attribute__((address_space(3)))
__device__ __forceinline__ void gload16(const _Float16* g, _Float16* l) {
    __builtin_amdgcn_global_load_lds((const AS1 unsigned int*)(g),
                                     (AS3 unsigned int*)(l), 16, 0, 0);
}

// ---------------- workspace layout (float slots) ----------------
constexpr size_t OFF_AH  = 0;
constexpr size_t OFF_WGT = OFF_AH + 2097152u;
constexpr size_t OFF_WUT = OFF_WGT + 6291456u;
constexpr size_t OFF_BG  = OFF_WUT + 3145728u;
constexpr size_t OFF_BU  = OFF_BG + 131072u;
constexpr size_t OFF_XT  = OFF_BU + 65536u;
constexpr size_t OFF_X2T = OFF_XT + 1048576u;
constexpr size_t OFF_SXT = OFF_X2T + 1048576u;
constexpr size_t OFF_HS  = OFF_SXT + 393216u;
constexpr size_t OFF_Y   = OFF_HS + 2097152u;
constexpr size_t OFF_AXP = OFF_Y + 4194304u;
constexpr size_t OFF_R   = OFF_AXP + 1572864u;
constexpr size_t OFF_ZH  = OFF_R + 1048576u;
// end = 24,182,784 floats = ~96.7 MB

// ---------------- fused preamble: adj | wg | wu | bias | setup (independent) ----------
// block ranges: [0,2048) adj, [2048,4096) wg, [4096,6144) wu,
//               [6144,6912) bias, [6912,15104) setup
__global__ __launch_bounds__(256) void pre_kernel(
    const float* __restrict__ E, const float* __restrict__ gW,
    const float* __restrict__ uW, const float* __restrict__ gb,
    const float* __restrict__ ub, const float* __restrict__ src,
    _Float16* __restrict__ Ah, _Float16* __restrict__ Wgt,
    _Float16* __restrict__ Wut, float* __restrict__ bg, float* __restrict__ bu,
    _Float16* __restrict__ XT, _Float16* __restrict__ X2T,
    _Float16* __restrict__ SXT, float* __restrict__ Hs) {
    __shared__ __align__(16) float pre_f[3168];  // union: adj 266 f, wg 3152 f, wu 1584 f
    const int bidg = blockIdx.x;
    const int t = threadIdx.x;

    if (bidg < 2048) {
        // ---- adj: A = softmax(relu(E E^T), axis=1) * ASCALE ----
        float* En = pre_f;
        float* red = pre_f + 16;
        const int n = bidg;
        if (t < ND) En[t] = E[n * ND + t];
        __syncthreads();
        float v[8];
        float mx = 0.f;
#pragma unroll
        for (int i = 0; i < 8; ++i) {
            const int m = t + i * 256;
            float acc = 0.f;
#pragma unroll
            for (int d = 0; d < ND; ++d) acc += En[d] * E[m * ND + d];
            acc = fmaxf(acc, 0.f);
            v[i] = acc;
            mx = fmaxf(mx, acc);
        }
        red[t] = mx;
        __syncthreads();
        for (int s = 128; s > 0; s >>= 1) {
            if (t < s) red[t] = fmaxf(red[t], red[t + s]);
            __syncthreads();
        }
        mx = red[0];
        __syncthreads();
        float sum = 0.f;
#pragma unroll
        for (int i = 0; i < 8; ++i) {
            v[i] = expf(v[i] - mx);
            sum += v[i];
        }
        red[t] = sum;
        __syncthreads();
        for (int s = 128; s > 0; s >>= 1) {
            if (t < s) red[t] += red[t + s];
            __syncthreads();
        }
        const float inv = ASCALE / red[0];
#pragma unroll
        for (int i = 0; i < 8; ++i)
            Ah[(size_t)n * NNODE + t + i * 256] = (_Float16)(v[i] * inv);
    } else if (bidg < 4096) {
        // ---- wg: per-node gate weights -> [n][o][k] via LDS transpose ----
        float* Es = pre_f;
        _Float16* Wl = (_Float16*)(pre_f + 16);  // 64*WPAD = 6272 halfs
        const int n = bidg - 2048;
        if (t < ND) Es[t] = E[n * ND + t];
        for (int i = t; i < 64 * WPAD / 2; i += 256) ((unsigned*)Wl)[i] = 0u;
        __syncthreads();
        for (int rem = t; rem < 4224; rem += 256) {
            float acc = 0.f;
#pragma unroll
            for (int d = 0; d < ND; ++d) acc += Es[d] * gW[d * 4224 + rem];
            const int kk = rem / 2112, r2 = rem % 2112;
            const int i = r2 >> 6, o = r2 & 63;
            Wl[o * WPAD + kk * 33 + i] = (_Float16)acc;
        }
        __syncthreads();
        const unsigned* wl = (const unsigned*)Wl;
        unsigned* dst = (unsigned*)(Wgt + (size_t)n * 6144);
        for (int idx = t; idx < 64 * 48; idx += 256) {
            const int o = idx / 48, j = idx % 48;
            dst[idx] = wl[o * (WPAD / 2) + j];
        }
    } else if (bidg < 6144) {
        // ---- wu ----
        float* Es = pre_f;
        _Float16* Wl = (_Float16*)(pre_f + 16);  // 32*WPAD = 3136 halfs
        const int n = bidg - 4096;
        if (t < ND) Es[t] = E[n * ND + t];
        for (int i = t; i < 32 * WPAD / 2; i += 256) ((unsigned*)Wl)[i] = 0u;
        __syncthreads();
        for (int rem = t; rem < 2112; rem += 256) {
            float acc = 0.f;
#pragma unroll
            for (int d = 0; d < ND; ++d) acc += Es[d] * uW[d * 2112 + rem];
            const int kk = rem / 1056, r2 = rem % 1056;
            const int i = r2 >> 5, o = r2 & 31;
            Wl[o * WPAD + kk * 33 + i] = (_Float16)acc;
        }
        __syncthreads();
        const unsigned* wl = (const unsigned*)Wl;
        unsigned* dst = (unsigned*)(Wut + (size_t)n * 3072);
        for (int idx = t; idx < 32 * 48; idx += 256) {
            const int o = idx / 48, j = idx % 48;
            dst[idx] = wl[o * (WPAD / 2) + j];
        }
    } else if (bidg < 6912) {
        // ---- bias ----
        const int idx = (bidg - 6144) * 256 + t;
        if (idx < NNODE * 64) {
            const int n = idx >> 6, o = idx & 63;
            float acc = 0.f;
#pragma unroll
            for (int d = 0; d < ND; ++d) acc += E[n * ND + d] * gb[d * 64 + o];
            bg[idx] = acc;
        } else {
            const int j = idx - NNODE * 64;
            const int n = j >> 5, o = j & 31;
            float acc = 0.f;
#pragma unroll
            for (int d = 0; d < ND; ++d) acc += E[n * ND + d] * ub[d * 32 + o];
            bu[j] = acc;
        }
    } else {
        // ---- setup: XT=0, X2T=0, Hs=0, SXT from src ----
        const int idx = (bidg - 6912) * 256 + t;  // over 2048*1024
        XT[idx] = (_Float16)0.f;
        X2T[idx] = (_Float16)0.f;
        Hs[idx] = 0.f;
        if (idx < NCX * NNODE) {
            const int col = idx >> 11, n = idx & 2047;
            const int tt = col >> 5, b = col & 31;
            SXT[idx] = (_Float16)src[((size_t)b * NT + tt) * NNODE + n];
        }
    }
}

// ---------------- Y_part[z] = (A*ASCALE) @ XT^T * (1/ASCALE), fp16 out ----------------
// BK=64: 8 k-iters (half the barrier drains of BK=32). LDS rows = 64 halfs (8
// 16B chunks), XOR-swizzled phys chunk p = c ^ (row&7). DMA lands pre-swizzled
// (source col ((lane&7)^(lane>>3))*8); fragment reads at p=(ks*4+q)^(lm&7) touch
// all 32 banks at 2-way (free). XCD k-split pinning via task&7 as before.
__global__ __launch_bounds__(256) void mm_kernel(const _Float16* __restrict__ Ah,
                                                 const _Float16* __restrict__ XT,
                                                 _Float16* __restrict__ Y, int nct) {
    __shared__ _Float16 As[128 * 64];
    __shared__ _Float16 Bs[128 * 64];
    const int t = threadIdx.x;
    const int bid = blockIdx.x;
    const int xcd = bid & 7;
    const int kz = xcd >> 1;
    const int s = (bid >> 3) * 2 + (xcd & 1);
    const int m0 = (s & 15) * 128;
    const int c0 = (s >> 4) * 128;
    const int ncols = nct << 7;
    _Float16* __restrict__ Yp = Y + (size_t)kz * NNODE * ncols;
    const int lane = t & 63;
    const int w = t >> 6;
    const int wm = (w & 1) * 64;
    const int wn = (w >> 1) * 64;
    const int lm = lane & 15;
    const int q = lane >> 4;

    // staging: wave w covers tile rows [w*32, w*32+32). Per gload16 j: lane ->
    // (row = w*32 + j*8 + (lane>>3), phys chunk = lane&7), source logical chunk
    // = (lane&7) ^ (lane>>3)  [= p ^ (row&7)].
    const int srow = w * 32 + (lane >> 3);
    const int sc = ((lane & 7) ^ (lane >> 3)) * 8;
    const _Float16* gA = Ah + (size_t)(m0 + srow) * NNODE + kz * KCHUNK + sc;
    const _Float16* gB = XT + (size_t)(c0 + srow) * NNODE + kz * KCHUNK + sc;
    _Float16* lA = As + w * 2048;
    _Float16* lB = Bs + w * 2048;

    floatx4 acc[4][4] = {};

    for (int kt = 0; kt < KCHUNK; kt += 64) {
#pragma unroll
        for (int j = 0; j < 4; ++j) {
            gload16(gA + (size_t)j * 8 * NNODE, lA + j * 512);
            gload16(gB + (size_t)j * 8 * NNODE, lB + j * 512);
        }
        gA += 64;
        gB += 64;
        __syncthreads();
#pragma unroll
        for (int ks = 0; ks < 2; ++ks) {
            const int pc = ((ks * 4 + q) ^ (lm & 7)) * 8;
            half8 af[4], bf[4];
#pragma unroll
            for (int mt = 0; mt < 4; ++mt)
                af[mt] = *(const half8*)&As[(wm + mt * 16 + lm) * 64 + pc];
#pragma unroll
            for (int nt = 0; nt < 4; ++nt)
                bf[nt] = *(const half8*)&Bs[(wn + nt * 16 + lm) * 64 + pc];
#pragma unroll
            for (int mt = 0; mt < 4; ++mt)
#pragma unroll
                for (int nt = 0; nt < 4; ++nt)
                    acc[mt][nt] = __builtin_amdgcn_mfma_f32_16x16x32_f16(
                        af[mt], bf[nt], acc[mt][nt], 0, 0, 0);
        }
        __syncthreads();
    }
#pragma unroll
    for (int mt = 0; mt < 4; ++mt) {
#pragma unroll
        for (int nt = 0; nt < 4; ++nt) {
            const int row = m0 + wm + mt * 16 + q * 4;
            const int col = c0 + wn + nt * 16 + lm;
#pragma unroll
            for (int r = 0; r < 4; ++r)
                Yp[(size_t)(row + r) * ncols + col] = (_Float16)(acc[mt][nt][r] * AINV);
        }
    }
}

#define CAT(nd, b, i) cat[((nd) * 32 + (b)) * GPAD + (i)]

// ---------------- gate: MFMA weight apply; writes X2T (h-cols), zh, rbuf ----------------
__global__ __launch_bounds__(256) void gate_kernel(const float* __restrict__ src, int tcur,
                                                   const _Float16* __restrict__ Y,
                                                   const _Float16* __restrict__ AXP,
                                                   const _Float16* __restrict__ Wgt,
                                                   const float* __restrict__ bg,
                                                   const float* __restrict__ Hs,
                                                   _Float16* __restrict__ X2T,
                                                   _Float16* __restrict__ zh,
                                                   _Float16* __restrict__ rbuf) {
    __shared__ __align__(16) _Float16 cat[4 * 32 * GPAD];
    const int t = threadIdx.x;
    const int n0 = blockIdx.x * 4;
    {
        const int pair = t >> 1, which = t & 1;
        const int nd = pair >> 5, b = pair & 31;
        const int n1 = n0 + nd;
        if (which == 0) {
            CAT(nd, b, 0) = (_Float16)src[((size_t)b * NT + tcur) * NNODE + n1];
            const float* hp = Hs + (size_t)n1 * 1024 + b * 32;
#pragma unroll
            for (int i = 0; i < 32; ++i) CAT(nd, b, 1 + i) = (_Float16)hp[i];
#pragma unroll
            for (int i = 66; i < KPAD; i += 2) *(unsigned*)&CAT(nd, b, i) = 0u;
        } else {
            const _Float16* ax = AXP + (size_t)n1 * NCX + tcur * 32 + b;
            CAT(nd, b, 33) = (_Float16)((float)ax[0] + (float)ax[AXPS] +
                                        (float)ax[2 * AXPS] + (float)ax[3 * AXPS]);
            const _Float16* yp = Y + (size_t)n1 * NCOL + b * 32;
#pragma unroll
            for (int i = 0; i < 32; ++i) {
                const float sv = (float)yp[i] + (float)yp[Y1S + i] +
                                 (float)yp[2 * Y1S + i] + (float)yp[3 * Y1S + i];
                CAT(nd, b, 34 + i) = (_Float16)sv;
            }
        }
    }
    __syncthreads();
    const int w = t >> 6, lane = t & 63, lm = lane & 15, q = lane >> 4;
    const int n = n0 + w;
    const _Float16* Wn = Wgt + (size_t)n * 6144;
    floatx4 acc[2][4] = {};
#pragma unroll
    for (int kt = 0; kt < 3; ++kt) {
        half8 af[2], bf[4];
#pragma unroll
        for (int mt = 0; mt < 2; ++mt)
            af[mt] = *(const half8*)&CAT(w, mt * 16 + lm, kt * 32 + q * 8);
#pragma unroll
        for (int nt = 0; nt < 4; ++nt)
            bf[nt] = *(const half8*)(Wn + (nt * 16 + lm) * KPAD + kt * 32 + q * 8);
#pragma unroll
        for (int mt = 0; mt < 2; ++mt)
#pragma unroll
            for (int nt = 0; nt < 4; ++nt)
                acc[mt][nt] = __builtin_amdgcn_mfma_f32_16x16x32_f16(
                    af[mt], bf[nt], acc[mt][nt], 0, 0, 0);
    }
#pragma unroll
    for (int nt = 0; nt < 4; ++nt) {
        const int o = nt * 16 + lm;
        const float bias = bg[n * 64 + o];
#pragma unroll
        for (int mt = 0; mt < 2; ++mt) {
#pragma unroll
            for (int r = 0; r < 4; ++r) {
                const int b = mt * 16 + q * 4 + r;
                const float s = 1.f / (1.f + expf(-(acc[mt][nt][r] + bias)));
                if (o < 32) {
                    const float hold = Hs[(size_t)n * 1024 + b * 32 + o];
                    const _Float16 zv = (_Float16)(s * hold);
                    zh[(size_t)n * 1024 + b * 32 + o] = zv;
                    X2T[(size_t)(b * 32 + o) * NNODE + n] = zv;
                } else {
                    rbuf[(size_t)n * 1024 + b * 32 + (o - 32)] = (_Float16)s;
                }
            }
        }
    }
}

// ---------------- update: MFMA weight apply; writes Hs (fp32) + XT (h-cols) ----------------
__global__ __launch_bounds__(256) void upd_kernel(const float* __restrict__ src, int tcur,
                                                  const _Float16* __restrict__ Y,
                                                  const _Float16* __restrict__ AXP,
                                                  const _Float16* __restrict__ Wut,
                                                  const float* __restrict__ bu,
                                                  const _Float16* __restrict__ zh,
                                                  const _Float16* __restrict__ rbuf,
                                                  float* __restrict__ Hs,
                                                  _Float16* __restrict__ XT) {
    __shared__ __align__(16) _Float16 cat[4 * 32 * GPAD];
    const int t = threadIdx.x;
    const int n0 = blockIdx.x * 4;
    {
        const int pair = t >> 1, which = t & 1;
        const int nd = pair >> 5, b = pair & 31;
        const int n1 = n0 + nd;
        if (which == 0) {
            CAT(nd, b, 0) = (_Float16)src[((size_t)b * NT + tcur) * NNODE + n1];
            const _Float16* zp = zh + (size_t)n1 * 1024 + b * 32;
#pragma unroll
            for (int i = 0; i < 32; ++i) CAT(nd, b, 1 + i) = zp[i];
#pragma unroll
            for (int i = 66; i < KPAD; i += 2) *(unsigned*)&CAT(nd, b, i) = 0u;
        } else {
            const _Float16* ax = AXP + (size_t)n1 * NCX + tcur * 32 + b;
            CAT(nd, b, 33) = (_Float16)((float)ax[0] + (float)ax[AXPS] +
                                        (float)ax[2 * AXPS] + (float)ax[3 * AXPS]);
            const _Float16* yp = Y + (size_t)n1 * NCOL + b * 32;
#pragma unroll
            for (int i = 0; i < 32; ++i) {
                const float sv = (float)yp[i] + (float)yp[Y1S + i] +
                                 (float)yp[2 * Y1S + i] + (float)yp[3 * Y1S + i];
                CAT(nd, b, 34 + i) = (_Float16)sv;
            }
        }
    }
    __syncthreads();
    const int w = t >> 6, lane = t & 63, lm = lane & 15, q = lane >> 4;
    const int n = n0 + w;
    const _Float16* Wn = Wut + (size_t)n * 3072;
    floatx4 acc[2][2] = {};
#pragma unroll
    for (int kt = 0; kt < 3; ++kt) {
        half8 af[2], bf[2];
#pragma unroll
        for (int mt = 0; mt < 2; ++mt)
            af[mt] = *(const half8*)&CAT(w, mt * 16 + lm, kt * 32 + q * 8);
#pragma unroll
        for (int nt = 0; nt < 2; ++nt)
            bf[nt] = *(const half8*)(Wn + (nt * 16 + lm) * KPAD + kt * 32 + q * 8);
#pragma unroll
        for (int mt = 0; mt < 2; ++mt)
#pragma unroll
            for (int nt = 0; nt < 2; ++nt)
                acc[mt][nt] = __builtin_amdgcn_mfma_f32_16x16x32_f16(
                    af[mt], bf[nt], acc[mt][nt], 0, 0, 0);
    }
#pragma unroll
    for (int nt = 0; nt < 2; ++nt) {
        const int o = nt * 16 + lm;
        const float bias = bu[n * 32 + o];
#pragma unroll
        for (int mt = 0; mt < 2; ++mt) {
#pragma unroll
            for (int r = 0; r < 4; ++r) {
                const int b = mt * 16 + q * 4 + r;
                const float hc = tanhf(acc[mt][nt][r] + bias);
                const float rr = (float)rbuf[(size_t)n * 1024 + b * 32 + o];
                const size_t hidx = (size_t)n * 1024 + b * 32 + o;
                const float hnew = rr * Hs[hidx] + (1.f - rr) * hc;
                Hs[hidx] = hnew;
                XT[(size_t)(b * 32 + o) * NNODE + n] = (_Float16)hnew;
            }
        }
    }
}

// ---------------- out[b,0,n,t] = dot(h[b,n,:], convW[t,:]) + convb[t] ----------------
__global__ __launch_bounds__(256) void out_kernel(const float* __restrict__ Hs,
                                                  const float* __restrict__ cw,
                                                  const float* __restrict__ cb,
                                                  float* __restrict__ out) {
    __shared__ float h[NB * NH];
    __shared__ float cws[NT * NH];
    __shared__ float cbs[NT];
    const int n = blockIdx.x;
    const int t = threadIdx.x;
    for (int i = t; i < NT * NH; i += 256) cws[i] = cw[i];
    if (t < NT) cbs[t] = cb[t];
    for (int i = t; i < NB * NH; i += 256) h[i] = Hs[(size_t)n * 1024 + i];
    __syncthreads();
    for (int p = t; p < NB * NT; p += 256) {
        const int b = p / NT, tt = p % NT;
        float acc = cbs[tt];
#pragma unroll
        for (int j = 0; j < NH; ++j) acc += h[b * NH + j] * cws[tt * NH + j];
        out[(size_t)b * NNODE * NT + (size_t)n * NT + tt] = acc;
    }
}

extern "C" void kernel_launch(void* const* d_in, const int* in_sizes, int n_in,
                              void* d_out, int out_size, void* d_ws, size_t ws_size,
                              hipStream_t stream) {
    const float* src  = (const float*)d_in[0];
    const float* E    = (const float*)d_in[1];
    const float* gW   = (const float*)d_in[2];
    const float* gb   = (const float*)d_in[3];
    const float* uW   = (const float*)d_in[4];
    const float* ub   = (const float*)d_in[5];
    const float* cw   = (const float*)d_in[6];
    const float* cb   = (const float*)d_in[7];
    float* out = (float*)d_out;

    float* ws = (float*)d_ws;
    _Float16* Ah  = (_Float16*)(ws + OFF_AH);
    _Float16* Wgt = (_Float16*)(ws + OFF_WGT);
    _Float16* Wut = (_Float16*)(ws + OFF_WUT);
    float* bg  = ws + OFF_BG;
    float* bu  = ws + OFF_BU;
    _Float16* XT  = (_Float16*)(ws + OFF_XT);
    _Float16* X2T = (_Float16*)(ws + OFF_X2T);
    _Float16* SXT = (_Float16*)(ws + OFF_SXT);
    float* Hs  = ws + OFF_HS;
    _Float16* Y   = (_Float16*)(ws + OFF_Y);
    _Float16* AXP = (_Float16*)(ws + OFF_AXP);
    _Float16* rb  = (_Float16*)(ws + OFF_R);
    _Float16* zh  = (_Float16*)(ws + OFF_ZH);

    // fused preamble: adj | wg | wu | bias | setup
    pre_kernel<<<15104, 256, 0, stream>>>(E, gW, uW, gb, ub, src,
                                          Ah, Wgt, Wut, bg, bu, XT, X2T, SXT, Hs);

    // A @ x_t for all 12 steps at once (384 cols, 3 col-tiles)
    mm_kernel<<<64 * 3, 256, 0, stream>>>(Ah, SXT, AXP, 3);

    for (int t = 0; t < NT; ++t) {
        mm_kernel<<<64 * 8, 256, 0, stream>>>(Ah, XT, Y, 8);
        gate_kernel<<<NNODE / 4, 256, 0, stream>>>(src, t, Y, AXP, Wgt, bg, Hs, X2T, zh, rb);
        mm_kernel<<<64 * 8, 256, 0, stream>>>(Ah, X2T, Y, 8);
        upd_kernel<<<NNODE / 4, 256, 0, stream>>>(src, t, Y, AXP, Wut, bu, zh, rb, Hs, XT);
    }
    out_kernel<<<NNODE, 256, 0, stream>>>(Hs, cw, cb, out);
}

// Round 14
// 1025.155 us; speedup vs baseline: 3.4716x; 1.0818x over previous
//
#include <hip/hip_runtime.h>
#include <hip/hip_bf16.h>
#include <math.h>

// Problem constants
// B=32, T=12, N=2048, C=1, D=10, K=2, H=32
#define NNODE 2048
#define NB 32
#define NT 12
#define NH 32
#define ND 10
#define NCOL 1024          // h columns
#define NCX 384            // (t,b) x columns
#define KPAD 96            // gconv K = 66, zero-padded to 3 MFMA k-tiles
#define GPAD 104           // LDS row stride (halfs) for cat tiles
#define WPAD 98            // LDS row stride for wg/wu transpose

#define ASCALE 256.0f
#define AINV 0.00390625f

#define KCHUNK 512
#define Y1S ((size_t)NNODE * NCOL)
#define AXPS ((size_t)NNODE * NCX)

typedef _Float16 half8 __attribute__((ext_vector_type(8)));
typedef float floatx4 __attribute__((ext_vector_type(4)));

#define AS1 __attribute__((address_space(1)))
#define AS3 __attribute__((address_space(3)))
__device__ __forceinline__ void gload16(const _Float16* g, _Float16* l) {
    __builtin_amdgcn_global_load_lds((const AS1 unsigned int*)(g),
                                     (AS3 unsigned int*)(l), 16, 0, 0);
}

// ---------------- workspace layout (float slots) ----------------
constexpr size_t OFF_AH  = 0;
constexpr size_t OFF_WGT = OFF_AH + 2097152u;
constexpr size_t OFF_WUT = OFF_WGT + 6291456u;
constexpr size_t OFF_BG  = OFF_WUT + 3145728u;
constexpr size_t OFF_BU  = OFF_BG + 131072u;
constexpr size_t OFF_XT  = OFF_BU + 65536u;
constexpr size_t OFF_X2T = OFF_XT + 1048576u;
constexpr size_t OFF_SXT = OFF_X2T + 1048576u;
constexpr size_t OFF_HS  = OFF_SXT + 393216u;
constexpr size_t OFF_Y   = OFF_HS + 2097152u;
constexpr size_t OFF_AXP = OFF_Y + 4194304u;
constexpr size_t OFF_R   = OFF_AXP + 1572864u;
constexpr size_t OFF_ZH  = OFF_R + 1048576u;
// end = 24,182,784 floats = ~96.7 MB

// ---------------- fused preamble: adj | wg | wu | bias | setup (independent) ----------
// block ranges: [0,2048) adj, [2048,4096) wg, [4096,6144) wu,
//               [6144,6912) bias, [6912,15104) setup (Hs=0, SXT)
// XT/X2T need no init: t=0 mms are skipped (h(0)=0) and upd(0)/gate(0)
// fully overwrite them before their first read.
__global__ __launch_bounds__(256) void pre_kernel(
    const float* __restrict__ E, const float* __restrict__ gW,
    const float* __restrict__ uW, const float* __restrict__ gb,
    const float* __restrict__ ub, const float* __restrict__ src,
    _Float16* __restrict__ Ah, _Float16* __restrict__ Wgt,
    _Float16* __restrict__ Wut, float* __restrict__ bg, float* __restrict__ bu,
    _Float16* __restrict__ SXT, float* __restrict__ Hs) {
    __shared__ __align__(16) float pre_f[3168];
    const int bidg = blockIdx.x;
    const int t = threadIdx.x;

    if (bidg < 2048) {
        // ---- adj: A = softmax(relu(E E^T), axis=1) * ASCALE ----
        float* En = pre_f;
        float* red = pre_f + 16;
        const int n = bidg;
        if (t < ND) En[t] = E[n * ND + t];
        __syncthreads();
        float v[8];
        float mx = 0.f;
#pragma unroll
        for (int i = 0; i < 8; ++i) {
            const int m = t + i * 256;
            float acc = 0.f;
#pragma unroll
            for (int d = 0; d < ND; ++d) acc += En[d] * E[m * ND + d];
            acc = fmaxf(acc, 0.f);
            v[i] = acc;
            mx = fmaxf(mx, acc);
        }
        red[t] = mx;
        __syncthreads();
        for (int s = 128; s > 0; s >>= 1) {
            if (t < s) red[t] = fmaxf(red[t], red[t + s]);
            __syncthreads();
        }
        mx = red[0];
        __syncthreads();
        float sum = 0.f;
#pragma unroll
        for (int i = 0; i < 8; ++i) {
            v[i] = expf(v[i] - mx);
            sum += v[i];
        }
        red[t] = sum;
        __syncthreads();
        for (int s = 128; s > 0; s >>= 1) {
            if (t < s) red[t] += red[t + s];
            __syncthreads();
        }
        const float inv = ASCALE / red[0];
#pragma unroll
        for (int i = 0; i < 8; ++i)
            Ah[(size_t)n * NNODE + t + i * 256] = (_Float16)(v[i] * inv);
    } else if (bidg < 4096) {
        // ---- wg ----
        float* Es = pre_f;
        _Float16* Wl = (_Float16*)(pre_f + 16);
        const int n = bidg - 2048;
        if (t < ND) Es[t] = E[n * ND + t];
        for (int i = t; i < 64 * WPAD / 2; i += 256) ((unsigned*)Wl)[i] = 0u;
        __syncthreads();
        for (int rem = t; rem < 4224; rem += 256) {
            float acc = 0.f;
#pragma unroll
            for (int d = 0; d < ND; ++d) acc += Es[d] * gW[d * 4224 + rem];
            const int kk = rem / 2112, r2 = rem % 2112;
            const int i = r2 >> 6, o = r2 & 63;
            Wl[o * WPAD + kk * 33 + i] = (_Float16)acc;
        }
        __syncthreads();
        const unsigned* wl = (const unsigned*)Wl;
        unsigned* dst = (unsigned*)(Wgt + (size_t)n * 6144);
        for (int idx = t; idx < 64 * 48; idx += 256) {
            const int o = idx / 48, j = idx % 48;
            dst[idx] = wl[o * (WPAD / 2) + j];
        }
    } else if (bidg < 6144) {
        // ---- wu ----
        float* Es = pre_f;
        _Float16* Wl = (_Float16*)(pre_f + 16);
        const int n = bidg - 4096;
        if (t < ND) Es[t] = E[n * ND + t];
        for (int i = t; i < 32 * WPAD / 2; i += 256) ((unsigned*)Wl)[i] = 0u;
        __syncthreads();
        for (int rem = t; rem < 2112; rem += 256) {
            float acc = 0.f;
#pragma unroll
            for (int d = 0; d < ND; ++d) acc += Es[d] * uW[d * 2112 + rem];
            const int kk = rem / 1056, r2 = rem % 1056;
            const int i = r2 >> 5, o = r2 & 31;
            Wl[o * WPAD + kk * 33 + i] = (_Float16)acc;
        }
        __syncthreads();
        const unsigned* wl = (const unsigned*)Wl;
        unsigned* dst = (unsigned*)(Wut + (size_t)n * 3072);
        for (int idx = t; idx < 32 * 48; idx += 256) {
            const int o = idx / 48, j = idx % 48;
            dst[idx] = wl[o * (WPAD / 2) + j];
        }
    } else if (bidg < 6912) {
        // ---- bias ----
        const int idx = (bidg - 6144) * 256 + t;
        if (idx < NNODE * 64) {
            const int n = idx >> 6, o = idx & 63;
            float acc = 0.f;
#pragma unroll
            for (int d = 0; d < ND; ++d) acc += E[n * ND + d] * gb[d * 64 + o];
            bg[idx] = acc;
        } else {
            const int j = idx - NNODE * 64;
            const int n = j >> 5, o = j & 31;
            float acc = 0.f;
#pragma unroll
            for (int d = 0; d < ND; ++d) acc += E[n * ND + d] * ub[d * 32 + o];
            bu[j] = acc;
        }
    } else {
        // ---- setup: Hs=0, SXT from src ----
        const int idx = (bidg - 6912) * 256 + t;  // over 2048*1024
        Hs[idx] = 0.f;
        if (idx < NCX * NNODE) {
            const int col = idx >> 11, n = idx & 2047;
            const int tt = col >> 5, b = col & 31;
            SXT[idx] = (_Float16)src[((size_t)b * NT + tt) * NNODE + n];
        }
    }
}

// ---------------- Y_part[z] = (A*ASCALE) @ XT^T * (1/ASCALE), fp16 out ----------------
// BK=64, XOR-swizzled LDS (p = c ^ (row&7)), DMA staging, XCD k-split pinning.
__global__ __launch_bounds__(256) void mm_kernel(const _Float16* __restrict__ Ah,
                                                 const _Float16* __restrict__ XT,
                                                 _Float16* __restrict__ Y, int nct) {
    __shared__ _Float16 As[128 * 64];
    __shared__ _Float16 Bs[128 * 64];
    const int t = threadIdx.x;
    const int bid = blockIdx.x;
    const int xcd = bid & 7;
    const int kz = xcd >> 1;
    const int s = (bid >> 3) * 2 + (xcd & 1);
    const int m0 = (s & 15) * 128;
    const int c0 = (s >> 4) * 128;
    const int ncols = nct << 7;
    _Float16* __restrict__ Yp = Y + (size_t)kz * NNODE * ncols;
    const int lane = t & 63;
    const int w = t >> 6;
    const int wm = (w & 1) * 64;
    const int wn = (w >> 1) * 64;
    const int lm = lane & 15;
    const int q = lane >> 4;

    const int srow = w * 32 + (lane >> 3);
    const int sc = ((lane & 7) ^ (lane >> 3)) * 8;
    const _Float16* gA = Ah + (size_t)(m0 + srow) * NNODE + kz * KCHUNK + sc;
    const _Float16* gB = XT + (size_t)(c0 + srow) * NNODE + kz * KCHUNK + sc;
    _Float16* lA = As + w * 2048;
    _Float16* lB = Bs + w * 2048;

    floatx4 acc[4][4] = {};

    for (int kt = 0; kt < KCHUNK; kt += 64) {
#pragma unroll
        for (int j = 0; j < 4; ++j) {
            gload16(gA + (size_t)j * 8 * NNODE, lA + j * 512);
            gload16(gB + (size_t)j * 8 * NNODE, lB + j * 512);
        }
        gA += 64;
        gB += 64;
        __syncthreads();
#pragma unroll
        for (int ks = 0; ks < 2; ++ks) {
            const int pc = ((ks * 4 + q) ^ (lm & 7)) * 8;
            half8 af[4], bf[4];
#pragma unroll
            for (int mt = 0; mt < 4; ++mt)
                af[mt] = *(const half8*)&As[(wm + mt * 16 + lm) * 64 + pc];
#pragma unroll
            for (int nt = 0; nt < 4; ++nt)
                bf[nt] = *(const half8*)&Bs[(wn + nt * 16 + lm) * 64 + pc];
#pragma unroll
            for (int mt = 0; mt < 4; ++mt)
#pragma unroll
                for (int nt = 0; nt < 4; ++nt)
                    acc[mt][nt] = __builtin_amdgcn_mfma_f32_16x16x32_f16(
                        af[mt], bf[nt], acc[mt][nt], 0, 0, 0);
        }
        __syncthreads();
    }
#pragma unroll
    for (int mt = 0; mt < 4; ++mt) {
#pragma unroll
        for (int nt = 0; nt < 4; ++nt) {
            const int row = m0 + wm + mt * 16 + q * 4;
            const int col = c0 + wn + nt * 16 + lm;
#pragma unroll
            for (int r = 0; r < 4; ++r)
                Yp[(size_t)(row + r) * ncols + col] = (_Float16)(acc[mt][nt][r] * AINV);
        }
    }
}

#define CAT(nd, b, i) cat[((nd) * 32 + (b)) * GPAD + (i)]

// ---------------- gate: MFMA weight apply; writes X2T (h-cols), zh, rbuf ----------------
// yzero: treat Y as exact zeros (t=0, h=0) without reading it.
__global__ __launch_bounds__(256) void gate_kernel(const float* __restrict__ src, int tcur,
                                                   const _Float16* __restrict__ Y,
                                                   const _Float16* __restrict__ AXP,
                                                   const _Float16* __restrict__ Wgt,
                                                   const float* __restrict__ bg,
                                                   const float* __restrict__ Hs,
                                                   _Float16* __restrict__ X2T,
                                                   _Float16* __restrict__ zh,
                                                   _Float16* __restrict__ rbuf,
                                                   int yzero) {
    __shared__ __align__(16) _Float16 cat[4 * 32 * GPAD];
    const int t = threadIdx.x;
    const int n0 = blockIdx.x * 4;
    {
        const int pair = t >> 1, which = t & 1;
        const int nd = pair >> 5, b = pair & 31;
        const int n1 = n0 + nd;
        if (which == 0) {
            CAT(nd, b, 0) = (_Float16)src[((size_t)b * NT + tcur) * NNODE + n1];
            const float* hp = Hs + (size_t)n1 * 1024 + b * 32;
#pragma unroll
            for (int i = 0; i < 32; ++i) CAT(nd, b, 1 + i) = (_Float16)hp[i];
#pragma unroll
            for (int i = 66; i < KPAD; i += 2) *(unsigned*)&CAT(nd, b, i) = 0u;
        } else {
            const _Float16* ax = AXP + (size_t)n1 * NCX + tcur * 32 + b;
            CAT(nd, b, 33) = (_Float16)((float)ax[0] + (float)ax[AXPS] +
                                        (float)ax[2 * AXPS] + (float)ax[3 * AXPS]);
            if (yzero) {
#pragma unroll
                for (int i = 0; i < 32; ++i) CAT(nd, b, 34 + i) = (_Float16)0.f;
            } else {
                const _Float16* yp = Y + (size_t)n1 * NCOL + b * 32;
#pragma unroll
                for (int i = 0; i < 32; ++i) {
                    const float sv = (float)yp[i] + (float)yp[Y1S + i] +
                                     (float)yp[2 * Y1S + i] + (float)yp[3 * Y1S + i];
                    CAT(nd, b, 34 + i) = (_Float16)sv;
                }
            }
        }
    }
    __syncthreads();
    const int w = t >> 6, lane = t & 63, lm = lane & 15, q = lane >> 4;
    const int n = n0 + w;
    const _Float16* Wn = Wgt + (size_t)n * 6144;
    floatx4 acc[2][4] = {};
#pragma unroll
    for (int kt = 0; kt < 3; ++kt) {
        half8 af[2], bf[4];
#pragma unroll
        for (int mt = 0; mt < 2; ++mt)
            af[mt] = *(const half8*)&CAT(w, mt * 16 + lm, kt * 32 + q * 8);
#pragma unroll
        for (int nt = 0; nt < 4; ++nt)
            bf[nt] = *(const half8*)(Wn + (nt * 16 + lm) * KPAD + kt * 32 + q * 8);
#pragma unroll
        for (int mt = 0; mt < 2; ++mt)
#pragma unroll
            for (int nt = 0; nt < 4; ++nt)
                acc[mt][nt] = __builtin_amdgcn_mfma_f32_16x16x32_f16(
                    af[mt], bf[nt], acc[mt][nt], 0, 0, 0);
    }
#pragma unroll
    for (int nt = 0; nt < 4; ++nt) {
        const int o = nt * 16 + lm;
        const float bias = bg[n * 64 + o];
#pragma unroll
        for (int mt = 0; mt < 2; ++mt) {
#pragma unroll
            for (int r = 0; r < 4; ++r) {
                const int b = mt * 16 + q * 4 + r;
                const float s = 1.f / (1.f + expf(-(acc[mt][nt][r] + bias)));
                if (o < 32) {
                    const float hold = Hs[(size_t)n * 1024 + b * 32 + o];
                    const _Float16 zv = (_Float16)(s * hold);
                    zh[(size_t)n * 1024 + b * 32 + o] = zv;
                    X2T[(size_t)(b * 32 + o) * NNODE + n] = zv;
                } else {
                    rbuf[(size_t)n * 1024 + b * 32 + (o - 32)] = (_Float16)s;
                }
            }
        }
    }
}

// ---------------- update: MFMA weight apply; writes Hs (fp32) + XT (h-cols) ---------
// yzero: treat Y as zeros (t=0). last: fuse the end_conv output (fp32 h -> exact).
__global__ __launch_bounds__(256) void upd_kernel(const float* __restrict__ src, int tcur,
                                                  const _Float16* __restrict__ Y,
                                                  const _Float16* __restrict__ AXP,
                                                  const _Float16* __restrict__ Wut,
                                                  const float* __restrict__ bu,
                                                  const _Float16* __restrict__ zh,
                                                  const _Float16* __restrict__ rbuf,
                                                  float* __restrict__ Hs,
                                                  _Float16* __restrict__ XT,
                                                  const float* __restrict__ cw,
                                                  const float* __restrict__ cb,
                                                  float* __restrict__ out,
                                                  int yzero, int last) {
    __shared__ __align__(16) _Float16 cat[4 * 32 * GPAD];
    __shared__ float hl[4 * 1024];  // fp32 h for fused out (exact vs Hs)
    const int t = threadIdx.x;
    const int n0 = blockIdx.x * 4;
    {
        const int pair = t >> 1, which = t & 1;
        const int nd = pair >> 5, b = pair & 31;
        const int n1 = n0 + nd;
        if (which == 0) {
            CAT(nd, b, 0) = (_Float16)src[((size_t)b * NT + tcur) * NNODE + n1];
            const _Float16* zp = zh + (size_t)n1 * 1024 + b * 32;
#pragma unroll
            for (int i = 0; i < 32; ++i) CAT(nd, b, 1 + i) = zp[i];
#pragma unroll
            for (int i = 66; i < KPAD; i += 2) *(unsigned*)&CAT(nd, b, i) = 0u;
        } else {
            const _Float16* ax = AXP + (size_t)n1 * NCX + tcur * 32 + b;
            CAT(nd, b, 33) = (_Float16)((float)ax[0] + (float)ax[AXPS] +
                                        (float)ax[2 * AXPS] + (float)ax[3 * AXPS]);
            if (yzero) {
#pragma unroll
                for (int i = 0; i < 32; ++i) CAT(nd, b, 34 + i) = (_Float16)0.f;
            } else {
                const _Float16* yp = Y + (size_t)n1 * NCOL + b * 32;
#pragma unroll
                for (int i = 0; i < 32; ++i) {
                    const float sv = (float)yp[i] + (float)yp[Y1S + i] +
                                     (float)yp[2 * Y1S + i] + (float)yp[3 * Y1S + i];
                    CAT(nd, b, 34 + i) = (_Float16)sv;
                }
            }
        }
    }
    __syncthreads();
    const int w = t >> 6, lane = t & 63, lm = lane & 15, q = lane >> 4;
    const int n = n0 + w;
    const _Float16* Wn = Wut + (size_t)n * 3072;
    floatx4 acc[2][2] = {};
#pragma unroll
    for (int kt = 0; kt < 3; ++kt) {
        half8 af[2], bf[2];
#pragma unroll
        for (int mt = 0; mt < 2; ++mt)
            af[mt] = *(const half8*)&CAT(w, mt * 16 + lm, kt * 32 + q * 8);
#pragma unroll
        for (int nt = 0; nt < 2; ++nt)
            bf[nt] = *(const half8*)(Wn + (nt * 16 + lm) * KPAD + kt * 32 + q * 8);
#pragma unroll
        for (int mt = 0; mt < 2; ++mt)
#pragma unroll
            for (int nt = 0; nt < 2; ++nt)
                acc[mt][nt] = __builtin_amdgcn_mfma_f32_16x16x32_f16(
                    af[mt], bf[nt], acc[mt][nt], 0, 0, 0);
    }
#pragma unroll
    for (int nt = 0; nt < 2; ++nt) {
        const int o = nt * 16 + lm;
        const float bias = bu[n * 32 + o];
#pragma unroll
        for (int mt = 0; mt < 2; ++mt) {
#pragma unroll
            for (int r = 0; r < 4; ++r) {
                const int b = mt * 16 + q * 4 + r;
                const float hc = tanhf(acc[mt][nt][r] + bias);
                const float rr = (float)rbuf[(size_t)n * 1024 + b * 32 + o];
                const size_t hidx = (size_t)n * 1024 + b * 32 + o;
                const float hnew = rr * Hs[hidx] + (1.f - rr) * hc;
                Hs[hidx] = hnew;
                XT[(size_t)(b * 32 + o) * NNODE + n] = (_Float16)hnew;
                if (last) hl[w * 1024 + b * 32 + o] = hnew;
            }
        }
    }
    if (last) {
        __syncthreads();
#pragma unroll
        for (int i = 0; i < 6; ++i) {
            const int p = i * 256 + t;
            const int nd = p / 384, rem = p % 384;
            const int b = rem / NT, tt = rem % NT;
            float acc2 = cb[tt];
            const float* hp = hl + nd * 1024 + b * 32;
#pragma unroll
            for (int j = 0; j < NH; ++j) acc2 += hp[j] * cw[tt * 32 + j];
            out[(size_t)b * NNODE * NT + (size_t)(n0 + nd) * NT + tt] = acc2;
        }
    }
}

extern "C" void kernel_launch(void* const* d_in, const int* in_sizes, int n_in,
                              void* d_out, int out_size, void* d_ws, size_t ws_size,
                              hipStream_t stream) {
    const float* src  = (const float*)d_in[0];
    const float* E    = (const float*)d_in[1];
    const float* gW   = (const float*)d_in[2];
    const float* gb   = (const float*)d_in[3];
    const float* uW   = (const float*)d_in[4];
    const float* ub   = (const float*)d_in[5];
    const float* cw   = (const float*)d_in[6];
    const float* cb   = (const float*)d_in[7];
    float* out = (float*)d_out;

    float* ws = (float*)d_ws;
    _Float16* Ah  = (_Float16*)(ws + OFF_AH);
    _Float16* Wgt = (_Float16*)(ws + OFF_WGT);
    _Float16* Wut = (_Float16*)(ws + OFF_WUT);
    float* bg  = ws + OFF_BG;
    float* bu  = ws + OFF_BU;
    _Float16* XT  = (_Float16*)(ws + OFF_XT);
    _Float16* X2T = (_Float16*)(ws + OFF_X2T);
    _Float16* SXT = (_Float16*)(ws + OFF_SXT);
    float* Hs  = ws + OFF_HS;
    _Float16* Y   = (_Float16*)(ws + OFF_Y);
    _Float16* AXP = (_Float16*)(ws + OFF_AXP);
    _Float16* rb  = (_Float16*)(ws + OFF_R);
    _Float16* zh  = (_Float16*)(ws + OFF_ZH);

    // fused preamble: adj | wg | wu | bias | setup
    pre_kernel<<<15104, 256, 0, stream>>>(E, gW, uW, gb, ub, src,
                                          Ah, Wgt, Wut, bg, bu, SXT, Hs);

    // A @ x_t for all 12 steps at once (384 cols, 3 col-tiles)
    mm_kernel<<<64 * 3, 256, 0, stream>>>(Ah, SXT, AXP, 3);

    for (int t = 0; t < NT; ++t) {
        if (t > 0)
            mm_kernel<<<64 * 8, 256, 0, stream>>>(Ah, XT, Y, 8);
        gate_kernel<<<NNODE / 4, 256, 0, stream>>>(src, t, Y, AXP, Wgt, bg, Hs,
                                                   X2T, zh, rb, t == 0);
        if (t > 0)
            mm_kernel<<<64 * 8, 256, 0, stream>>>(Ah, X2T, Y, 8);
        upd_kernel<<<NNODE / 4, 256, 0, stream>>>(src, t, Y, AXP, Wut, bu, zh, rb,
                                                  Hs, XT, cw, cb, out,
                                                  t == 0, t == NT - 1);
    }
}